// Round 5
// baseline (492.391 us; speedup 1.0000x reference)
//
#include <hip/hip_runtime.h>

#define SEQ   4096
#define NB    32
#define DI    64
#define NS    16
#define CHUNK 128
#define NCHUNK (SEQ / CHUNK)

// ws layout (floats):
//  dtT [32][64][4096]  @ 0
//  xT  [32][64][4096]  @ 8388608
//  BT  [32][16][4096]  @ 16777216
//  CT  [32][16][4096]  @ 18874368

__device__ __forceinline__ void async_copy16(const float* g, float* l) {
  __builtin_amdgcn_global_load_lds(
      (const __attribute__((address_space(1))) void*)g,
      (__attribute__((address_space(3))) void*)l, 16, 0, 0);
}

// row_shl:k (0x100|k): lane i <- lane i+k within the 16-lane row; invalid
// lanes get old (=0). Chain 8,4,2,1 => lane 0 of each row holds the row sum.
template <int CTRL>
__device__ __forceinline__ float dpp_add(float s) {
  return s + __int_as_float(__builtin_amdgcn_update_dpp(
                 0, __float_as_int(s), CTRL, 0xf, 0xf, false));
}

// ---------------- Phase 1: per-row projections + transpose ----------------
__global__ __launch_bounds__(256) void ssm_prep(
    const float* __restrict__ x, const float* __restrict__ Wx,
    const float* __restrict__ bx, const float* __restrict__ Wdt,
    const float* __restrict__ bdt, float* __restrict__ ws) {
  __shared__ float xtile[64 * 65];
  __shared__ float ytile[96 * 65];
  const int tid = threadIdx.x;
  const int w = tid >> 6;        // wave 0..3
  const int l = tid & 63;        // lane
  const int b = blockIdx.x >> 6;
  const int t0 = (blockIdx.x & 63) << 6;

  // per-lane weights: lane j (j<36) owns Wx row j; every lane owns Wdt row l
  const int lr = l < 36 ? l : 35;
  float wrow[64];
#pragma unroll
  for (int i = 0; i < 16; ++i) {
    const float4 v = ((const float4*)(Wx + lr * 64))[i];
    wrow[4 * i + 0] = v.x; wrow[4 * i + 1] = v.y;
    wrow[4 * i + 2] = v.z; wrow[4 * i + 3] = v.w;
  }
  const float bxv = bx[lr];
  const float4 wdtv = ((const float4*)Wdt)[l];
  const float bdtv = bdt[l];

  // prefetch this wave's 16 rows of x
  float xiv[16];
#pragma unroll
  for (int i = 0; i < 16; ++i)
    xiv[i] = x[((size_t)b * SEQ + (t0 + (w << 4) + i)) * 64 + l];

#pragma unroll
  for (int i = 0; i < 16; ++i) {
    const int tt = (w << 4) + i;
    const float xi = xiv[i];
    xtile[l * 65 + tt] = xi;
    const int xibits = __float_as_int(xi);
    float acc0 = bxv, acc1 = 0.f;
#pragma unroll
    for (int dj = 0; dj < 64; dj += 2) {
      acc0 = fmaf(wrow[dj],     __int_as_float(__builtin_amdgcn_readlane(xibits, dj)),     acc0);
      acc1 = fmaf(wrow[dj + 1], __int_as_float(__builtin_amdgcn_readlane(xibits, dj + 1)), acc1);
    }
    const float acc = acc0 + acc1;       // xp[l] valid for l<36
    const int ab = __float_as_int(acc);
    float dtv = bdtv;
    dtv = fmaf(wdtv.x, __int_as_float(__builtin_amdgcn_readlane(ab, 16)), dtv);
    dtv = fmaf(wdtv.y, __int_as_float(__builtin_amdgcn_readlane(ab, 17)), dtv);
    dtv = fmaf(wdtv.z, __int_as_float(__builtin_amdgcn_readlane(ab, 18)), dtv);
    dtv = fmaf(wdtv.w, __int_as_float(__builtin_amdgcn_readlane(ab, 19)), dtv);
    ytile[l * 65 + tt] = dtv;                                   // dt rows 0..63
    if (l < 16)                ytile[(64 + l) * 65 + tt] = acc; // B rows 64..79
    else if (l >= 20 && l < 36) ytile[(60 + l) * 65 + tt] = acc; // C rows 80..95
  }
  __syncthreads();

  float* dtT = ws;
  float* xT  = ws + 8388608;
  float* BT  = ws + 16777216;
  float* CT  = ws + 18874368;
  for (int R = w; R < 160; R += 4) {
    const float v = (R < 64) ? xtile[R * 65 + l] : ytile[(R - 64) * 65 + l];
    float* dst;
    if (R < 64)       dst = xT  + ((size_t)b * 64 + R) * SEQ;
    else if (R < 128) dst = dtT + ((size_t)b * 64 + (R - 64)) * SEQ;
    else if (R < 144) dst = BT  + ((size_t)b * 16 + (R - 128)) * SEQ;
    else              dst = CT  + ((size_t)b * 16 + (R - 144)) * SEQ;
    dst[t0 + l] = v;
  }
}

// ---------------- Phase 2: sequential scan, thread = (b,d,n) cell ----------
__global__ __launch_bounds__(64) void ssm_scan(
    const float* __restrict__ ws, const float* __restrict__ A_log,
    const float* __restrict__ Dp, float* __restrict__ out,
    float* __restrict__ hidden) {
  __shared__ __align__(16) float buf[2][40 * CHUNK];
  const int lane = threadIdx.x;
  // XCD swizzle: all 16 d-group blocks of one batch land on the same XCD
  const int j = blockIdx.x;
  const int o = ((j & 7) << 6) + (j >> 3);
  const int b = o >> 4;
  const int dg = o & 15;
  const int d0 = dg << 2;
  const int dd = lane >> 4;
  const int n  = lane & 15;
  const int d  = d0 + dd;

  const float Av  = -expf(A_log[d * 16 + n]);
  const float Dpv = Dp[d];

  const float* dtT = ws;
  const float* xT  = ws + 8388608;
  const float* BT  = ws + 16777216;
  const float* CT  = ws + 18874368;

  const int hf = lane >> 5;          // which of the 2 rows this lane stages
  const int u4 = (lane & 31) << 2;   // word offset within the row
  const int xa = dd << 2;            // read swizzle for dt/x rows
  const int xb = (n & 7) << 2;       // read swizzle for B/C rows

  // stage 40 rows x 128 floats into dstbuf; LDS linear, source XOR-swizzled
  auto stage = [&](float* dstbuf, int tbase) {
#pragma unroll
    for (int i = 0; i < 20; ++i) {
      const int r = 2 * i + hf;      // 0-3 dt | 4-7 x | 8-23 B | 24-39 C
      const float* p0 = dtT + ((size_t)b * 64 + d0 + r) * SEQ;
      const float* p1 = xT  + ((size_t)b * 64 + d0 + (r - 4)) * SEQ;
      const float* p2 = BT  + ((size_t)b * 16 + (r - 8)) * SEQ;
      const float* p3 = CT  + ((size_t)b * 16 + (r - 24)) * SEQ;
      const float* base = r < 4 ? p0 : (r < 8 ? p1 : (r < 24 ? p2 : p3));
      const int tsrc = u4 ^ ((r & 7) << 2);
      async_copy16(base + tbase + tsrc, dstbuf + i * 256);
    }
  };

  float h = 0.f;
  float* hidp = hidden + (size_t)b * SEQ * 1024 + d0 * 16 + lane;
  float* outp = out + (size_t)b * SEQ * 64 + d0 + dd;

  stage(buf[0], 0);
  asm volatile("s_waitcnt vmcnt(0)" ::: "memory");
  int cur = 0;

  for (int c = 0; c < NCHUNK; ++c) {
    if (c + 1 < NCHUNK) stage(buf[cur ^ 1], (c + 1) * CHUNK);
    const float* bc = buf[cur];

    for (int tb = 0; tb < CHUNK; tb += 4) {
      const float4 dtq = *(const float4*)(bc + dd * 128 + (tb ^ xa));
      const float4 xq  = *(const float4*)(bc + (4 + dd) * 128 + ((tb ^ xa) ^ 16));
      const float4 Bq  = *(const float4*)(bc + (8 + n) * 128 + (tb ^ xb));
      const float4 Cq  = *(const float4*)(bc + (24 + n) * 128 + (tb ^ xb));
      const float dta[4] = {dtq.x, dtq.y, dtq.z, dtq.w};
      const float xar[4] = {xq.x,  xq.y,  xq.z,  xq.w};
      const float Ba[4]  = {Bq.x,  Bq.y,  Bq.z,  Bq.w};
      const float Ca[4]  = {Cq.x,  Cq.y,  Cq.z,  Cq.w};
#pragma unroll
      for (int q = 0; q < 4; ++q) {
        const int tq = tb + q;
        h = fmaf(h, dta[q] * Av, (xar[q] * dta[q]) * Ba[q]);
        h = fminf(fmaxf(h, -1000000.0f), 1000000.0f);
        hidp[(size_t)tq * 1024] = h;
        float s = h * Ca[q];
        s = dpp_add<0x108>(s);   // row_shl:8  (lane i <- lane i+8)
        s = dpp_add<0x104>(s);   // row_shl:4
        s = dpp_add<0x102>(s);   // row_shl:2
        s = dpp_add<0x101>(s);   // row_shl:1  -> lane n==0 has full row sum
        if (n == 0) outp[(size_t)tq * 64] = fmaf(Dpv, xar[q], s);
      }
    }
    asm volatile("s_waitcnt vmcnt(0)" ::: "memory");
    __builtin_amdgcn_sched_barrier(0);
    cur ^= 1;
    hidp += (size_t)CHUNK * 1024;
    outp += (size_t)CHUNK * 64;
  }
}

extern "C" void kernel_launch(void* const* d_in, const int* in_sizes, int n_in,
                              void* d_out, int out_size, void* d_ws, size_t ws_size,
                              hipStream_t stream) {
  (void)in_sizes; (void)n_in; (void)out_size; (void)ws_size;
  const float* x     = (const float*)d_in[0];
  const float* Wx    = (const float*)d_in[1];
  const float* bx    = (const float*)d_in[2];
  const float* Wdt   = (const float*)d_in[3];
  const float* bdt   = (const float*)d_in[4];
  const float* A_log = (const float*)d_in[5];
  const float* Dp    = (const float*)d_in[6];
  float* out    = (float*)d_out;
  float* hidden = out + (size_t)NB * SEQ * DI;
  float* ws     = (float*)d_ws;

  ssm_prep<<<dim3(2048), dim3(256), 0, stream>>>(x, Wx, bx, Wdt, bdt, ws);
  ssm_scan<<<dim3(512), dim3(64), 0, stream>>>(ws, A_log, Dp, out, hidden);
}

// Round 6
// 254.294 us; speedup vs baseline: 1.9363x; 1.9363x over previous
//
#include <hip/hip_runtime.h>

#define SEQ    4096
#define NB     32
#define Nb     8          // chunks per sequence
#define CSTEPS 512        // steps per chunk (SEQ/NC)
#define CHUNK  32         // staged sub-chunk
#define NSUB   (CSTEPS / CHUNK)

// ws layout (floats):
//  dtT [32][64][4096]  @ 0
//  xT  [32][64][4096]  @ 8388608
//  BT  [32][16][4096]  @ 16777216
//  CT  [32][16][4096]  @ 18874368
//  Pp  float2 [512][8][64]  @ 20971520   (P, p per cell/chunk)
//  Hin float  [512][8][64]  @ 21495808   (carry-in h)

__device__ __forceinline__ void async_copy16(const float* g, float* l) {
  __builtin_amdgcn_global_load_lds(
      (const __attribute__((address_space(1))) void*)g,
      (__attribute__((address_space(3))) void*)l, 16, 0, 0);
}

// row_shl:k (0x100|k): lane i <- lane i+k; invalid lanes contribute old (=0).
template <int CTRL>
__device__ __forceinline__ float dpp_add(float s) {
  return s + __int_as_float(__builtin_amdgcn_update_dpp(
                 0, __float_as_int(s), CTRL, 0xf, 0xf, false));
}

// ---------------- Phase 1: per-row projections + transpose ----------------
__global__ __launch_bounds__(256) void ssm_prep(
    const float* __restrict__ x, const float* __restrict__ Wx,
    const float* __restrict__ bx, const float* __restrict__ Wdt,
    const float* __restrict__ bdt, float* __restrict__ ws) {
  __shared__ float xtile[64 * 65];
  __shared__ float ytile[96 * 65];
  const int tid = threadIdx.x;
  const int w = tid >> 6;
  const int l = tid & 63;
  const int b = blockIdx.x >> 6;
  const int t0 = (blockIdx.x & 63) << 6;

  const int lr = l < 36 ? l : 35;
  float wrow[64];
#pragma unroll
  for (int i = 0; i < 16; ++i) {
    const float4 v = ((const float4*)(Wx + lr * 64))[i];
    wrow[4 * i + 0] = v.x; wrow[4 * i + 1] = v.y;
    wrow[4 * i + 2] = v.z; wrow[4 * i + 3] = v.w;
  }
  const float bxv = bx[lr];
  const float4 wdtv = ((const float4*)Wdt)[l];
  const float bdtv = bdt[l];

  float xiv[16];
#pragma unroll
  for (int i = 0; i < 16; ++i)
    xiv[i] = x[((size_t)b * SEQ + (t0 + (w << 4) + i)) * 64 + l];

#pragma unroll
  for (int i = 0; i < 16; ++i) {
    const int tt = (w << 4) + i;
    const float xi = xiv[i];
    xtile[l * 65 + tt] = xi;
    const int xibits = __float_as_int(xi);
    float acc0 = bxv, acc1 = 0.f;
#pragma unroll
    for (int dj = 0; dj < 64; dj += 2) {
      acc0 = fmaf(wrow[dj],     __int_as_float(__builtin_amdgcn_readlane(xibits, dj)),     acc0);
      acc1 = fmaf(wrow[dj + 1], __int_as_float(__builtin_amdgcn_readlane(xibits, dj + 1)), acc1);
    }
    const float acc = acc0 + acc1;
    const int ab = __float_as_int(acc);
    float dtv = bdtv;
    dtv = fmaf(wdtv.x, __int_as_float(__builtin_amdgcn_readlane(ab, 16)), dtv);
    dtv = fmaf(wdtv.y, __int_as_float(__builtin_amdgcn_readlane(ab, 17)), dtv);
    dtv = fmaf(wdtv.z, __int_as_float(__builtin_amdgcn_readlane(ab, 18)), dtv);
    dtv = fmaf(wdtv.w, __int_as_float(__builtin_amdgcn_readlane(ab, 19)), dtv);
    ytile[l * 65 + tt] = dtv;
    if (l < 16)                 ytile[(64 + l) * 65 + tt] = acc;
    else if (l >= 20 && l < 36) ytile[(60 + l) * 65 + tt] = acc;
  }
  __syncthreads();

  float* dtT = ws;
  float* xT  = ws + 8388608;
  float* BT  = ws + 16777216;
  float* CT  = ws + 18874368;
  for (int R = w; R < 160; R += 4) {
    const float v = (R < 64) ? xtile[R * 65 + l] : ytile[(R - 64) * 65 + l];
    float* dst;
    if (R < 64)       dst = xT  + ((size_t)b * 64 + R) * SEQ;
    else if (R < 128) dst = dtT + ((size_t)b * 64 + (R - 64)) * SEQ;
    else if (R < 144) dst = BT  + ((size_t)b * 16 + (R - 128)) * SEQ;
    else              dst = CT  + ((size_t)b * 16 + (R - 144)) * SEQ;
    dst[t0 + l] = v;
  }
}

// ---------------- Phase 2a: per-chunk aggregates (P = prod dA, p = zsr) ----
__global__ __launch_bounds__(64, 4) void ssm_agg(
    const float* __restrict__ ws, const float* __restrict__ A_log,
    float2* __restrict__ Pp) {
  __shared__ __align__(16) float buf[2][24 * CHUNK];
  const int lane = threadIdx.x;
  const int id = blockIdx.x;            // ((b*16+dg)*NC + c)
  const int c  = id & 7;
  const int dg = (id >> 3) & 15;
  const int b  = id >> 7;
  const int d0 = dg << 2;
  const int dd = lane >> 4;
  const int n  = lane & 15;

  const float Av = -expf(A_log[(d0 + dd) * 16 + n]);

  const float* dtT = ws;
  const float* xT  = ws + 8388608;
  const float* BT  = ws + 16777216;

  auto stage = [&](float* dstbuf, int tbase) {
#pragma unroll
    for (int i = 0; i < 3; ++i) {
      const int g = i * 64 + lane;
      const int r = g >> 3;            // 0-3 dt | 4-7 x | 8-23 B
      const int c4 = (g & 7) << 2;
      const float* base;
      int xs;
      if (r < 8) { base = (r < 4 ? dtT + ((size_t)b * 64 + d0 + r) * SEQ
                                 : xT  + ((size_t)b * 64 + d0 + (r - 4)) * SEQ);
                   xs = (r & 7) << 2; }
      else       { base = BT + ((size_t)b * 16 + (r - 8)) * SEQ;
                   xs = ((r - 8) & 7) << 2; }
      async_copy16(base + tbase + (c4 ^ xs), dstbuf + i * 256);
    }
  };

  float P = 1.f, p = 0.f;
  stage(buf[0], c * CSTEPS);
  asm volatile("s_waitcnt vmcnt(0)" ::: "memory");
  int cur = 0;
  for (int sc = 0; sc < NSUB; ++sc) {
    if (sc + 1 < NSUB) stage(buf[cur ^ 1], c * CSTEPS + (sc + 1) * CHUNK);
    const float* bc = buf[cur];
    for (int tb = 0; tb < CHUNK; tb += 4) {
      const float4 dtq = *(const float4*)(bc + dd * 32 + (tb ^ (dd << 2)));
      const float4 xq  = *(const float4*)(bc + (4 + dd) * 32 + ((tb ^ (dd << 2)) ^ 16));
      const float4 Bq  = *(const float4*)(bc + (8 + n) * 32 + (tb ^ ((n & 7) << 2)));
      const float dta[4] = {dtq.x, dtq.y, dtq.z, dtq.w};
      const float xar[4] = {xq.x,  xq.y,  xq.z,  xq.w};
      const float Ba[4]  = {Bq.x,  Bq.y,  Bq.z,  Bq.w};
#pragma unroll
      for (int q = 0; q < 4; ++q) {
        const float dA = dta[q] * Av;
        p = fmaf(p, dA, (xar[q] * dta[q]) * Ba[q]);
        P *= dA;
      }
    }
    asm volatile("s_waitcnt vmcnt(0)" ::: "memory");
    __builtin_amdgcn_sched_barrier(0);
    cur ^= 1;
  }
  Pp[(size_t)id * 64 + lane] = make_float2(P, p);
}

// ---------------- Phase 2b: serial carry across chunks ---------------------
__global__ __launch_bounds__(64) void ssm_carry(
    const float2* __restrict__ Pp, float* __restrict__ Hin) {
  const int lane = threadIdx.x;
  const int bg = blockIdx.x;            // b*16+dg
  float H = 0.f;
#pragma unroll
  for (int c = 0; c < NB; ++c) {
    const size_t idx = ((size_t)bg * NB + c) * 64 + lane;
    const float2 pp = Pp[idx];
    Hin[idx] = H;
    H = fmaf(pp.x, H, pp.y);
  }
}

// ---------------- Phase 2c: exact scan per chunk with carry-in h -----------
__global__ __launch_bounds__(64, 4) void ssm_scan(
    const float* __restrict__ ws, const float* __restrict__ A_log,
    const float* __restrict__ Dp, const float* __restrict__ Hin,
    float* __restrict__ out, float* __restrict__ hidden) {
  __shared__ __align__(16) float buf[2][40 * CHUNK];
  const int lane = threadIdx.x;
  const int id = blockIdx.x;            // ((b*16+dg)*NC + c)
  const int c  = id & 7;
  const int dg = (id >> 3) & 15;
  const int b  = id >> 7;
  const int d0 = dg << 2;
  const int dd = lane >> 4;
  const int n  = lane & 15;
  const int d  = d0 + dd;

  const float Av  = -expf(A_log[d * 16 + n]);
  const float Dpv = Dp[d];

  const float* dtT = ws;
  const float* xT  = ws + 8388608;
  const float* BT  = ws + 16777216;
  const float* CT  = ws + 18874368;

  auto stage = [&](float* dstbuf, int tbase) {
#pragma unroll
    for (int i = 0; i < 5; ++i) {
      const int g = i * 64 + lane;
      const int r = g >> 3;            // 0-3 dt | 4-7 x | 8-23 B | 24-39 C
      const int c4 = (g & 7) << 2;
      const float* base;
      int xs;
      if (r < 8)       { base = (r < 4 ? dtT + ((size_t)b * 64 + d0 + r) * SEQ
                                       : xT  + ((size_t)b * 64 + d0 + (r - 4)) * SEQ);
                         xs = (r & 7) << 2; }
      else if (r < 24) { base = BT + ((size_t)b * 16 + (r - 8)) * SEQ;
                         xs = ((r - 8) & 7) << 2; }
      else             { base = CT + ((size_t)b * 16 + (r - 24)) * SEQ;
                         xs = ((r - 24) & 7) << 2; }
      async_copy16(base + tbase + (c4 ^ xs), dstbuf + i * 256);
    }
  };

  float h = Hin[(size_t)id * 64 + lane];
  const int tstart = c * CSTEPS;
  float* hidp = hidden + (size_t)b * SEQ * 1024 + (size_t)tstart * 1024 + d0 * 16 + lane;
  float* outp = out + (size_t)b * SEQ * 64 + (size_t)tstart * 64 + d;

  stage(buf[0], tstart);
  asm volatile("s_waitcnt vmcnt(0)" ::: "memory");
  int cur = 0;

  for (int sc = 0; sc < NSUB; ++sc) {
    if (sc + 1 < NSUB) stage(buf[cur ^ 1], tstart + (sc + 1) * CHUNK);
    const float* bc = buf[cur];

    for (int tb = 0; tb < CHUNK; tb += 4) {
      const float4 dtq = *(const float4*)(bc + dd * 32 + (tb ^ (dd << 2)));
      const float4 xq  = *(const float4*)(bc + (4 + dd) * 32 + ((tb ^ (dd << 2)) ^ 16));
      const float4 Bq  = *(const float4*)(bc + (8 + n) * 32 + (tb ^ ((n & 7) << 2)));
      const float4 Cq  = *(const float4*)(bc + (24 + n) * 32 + (tb ^ ((n & 7) << 2)));
      const float dta[4] = {dtq.x, dtq.y, dtq.z, dtq.w};
      const float xar[4] = {xq.x,  xq.y,  xq.z,  xq.w};
      const float Ba[4]  = {Bq.x,  Bq.y,  Bq.z,  Bq.w};
      const float Ca[4]  = {Cq.x,  Cq.y,  Cq.z,  Cq.w};
#pragma unroll
      for (int q = 0; q < 4; ++q) {
        const int tq = tb + q;
        h = fmaf(h, dta[q] * Av, (xar[q] * dta[q]) * Ba[q]);
        h = fminf(fmaxf(h, -1000000.0f), 1000000.0f);
        hidp[(size_t)tq * 1024] = h;
        float s = h * Ca[q];
        s = dpp_add<0x108>(s);   // row_shl:8
        s = dpp_add<0x104>(s);   // row_shl:4
        s = dpp_add<0x102>(s);   // row_shl:2
        s = dpp_add<0x101>(s);   // row_shl:1 -> lane n==0 has row sum
        if (n == 0) outp[(size_t)tq * 64] = fmaf(Dpv, xar[q], s);
      }
    }
    asm volatile("s_waitcnt vmcnt(0)" ::: "memory");
    __builtin_amdgcn_sched_barrier(0);
    cur ^= 1;
    hidp += (size_t)CHUNK * 1024;
    outp += (size_t)CHUNK * 64;
  }
}

extern "C" void kernel_launch(void* const* d_in, const int* in_sizes, int n_in,
                              void* d_out, int out_size, void* d_ws, size_t ws_size,
                              hipStream_t stream) {
  (void)in_sizes; (void)n_in; (void)out_size; (void)ws_size;
  const float* x     = (const float*)d_in[0];
  const float* Wx    = (const float*)d_in[1];
  const float* bx    = (const float*)d_in[2];
  const float* Wdt   = (const float*)d_in[3];
  const float* bdt   = (const float*)d_in[4];
  const float* A_log = (const float*)d_in[5];
  const float* Dp    = (const float*)d_in[6];
  float* out    = (float*)d_out;
  float* hidden = out + (size_t)NB * SEQ * 64;
  float* ws     = (float*)d_ws;
  float2* Pp    = (float2*)(ws + 20971520);
  float*  HinP  = ws + 21495808;

  ssm_prep<<<dim3(2048), dim3(256), 0, stream>>>(x, Wx, bx, Wdt, bdt, ws);
  ssm_agg<<<dim3(4096), dim3(64), 0, stream>>>(ws, A_log, Pp);
  ssm_carry<<<dim3(512), dim3(64), 0, stream>>>(Pp, HinP);
  ssm_scan<<<dim3(4096), dim3(64), 0, stream>>>(ws, A_log, Dp, HinP, out, hidden);
}